// Round 3
// baseline (13920.265 us; speedup 1.0000x reference)
//
#include <hip/hip_runtime.h>
#include <math.h>

#define N_NODES 50000
#define N_EDGES 100000
#define EP (N_EDGES + N_NODES)   // edges including self-loops
#define H 768
#define NH 12
#define HD 64
#define NG 64
#define NC 10
#define H2 384

// ---------------- static device scratch (avoids d_ws entirely) ----------------
// Uninitialized __device__ arrays land in the code object's .bss: allocated at
// module load (~322 MB of 288 GB HBM), zero file-size cost, capture-safe.
__device__ float    g_bufA[(size_t)N_NODES * H];
__device__ float    g_bufB[(size_t)N_NODES * H];
__device__ float    g_dinv[N_NODES];
__device__ float    g_aS[(size_t)N_NODES * NH];
__device__ float    g_aD[(size_t)N_NODES * NH];
__device__ unsigned g_mb[(size_t)N_NODES * NH];   // max-encode then decoded float
__device__ float    g_sb[(size_t)N_NODES * NH];
__device__ float    g_exb[(size_t)EP * NH];
__device__ float    g_pool[(size_t)NG * H];
__device__ float    g_cnt[NG];
__device__ float    g_zb[(size_t)NG * H2];

__device__ inline int clampi(int v, int hi) { return (v < 0) ? 0 : (v >= hi ? hi - 1 : v); }

// ---------------- utility ----------------
__global__ void fill_f32(float* p, int n, float v) {
    int i = blockIdx.x * blockDim.x + threadIdx.x;
    if (i < n) p[i] = v;
}

__global__ void fill_u32(unsigned* p, int n, unsigned v) {
    int i = blockIdx.x * blockDim.x + threadIdx.x;
    if (i < n) p[i] = v;
}

__global__ void edge_deg(const int* __restrict__ dst, float* deg) {
    int e = blockIdx.x * blockDim.x + threadIdx.x;
    if (e < N_EDGES) atomicAdd(&deg[clampi(dst[e], N_NODES)], 1.0f);
}

__global__ void rsqrt_inplace(float* p, int n) {
    int i = blockIdx.x * blockDim.x + threadIdx.x;
    if (i < n) p[i] = rsqrtf(p[i]);
}

// ---------------- GEMMs ----------------
// h = x @ w1 : [N,3] @ [3,H]
__global__ void gemm_k3(const float* __restrict__ x, const float* __restrict__ w,
                        float* __restrict__ out) {
    int idx = blockIdx.x * blockDim.x + threadIdx.x;
    if (idx >= N_NODES * H) return;
    int n = idx / H, j = idx % H;
    float x0 = x[n*3], x1 = x[n*3+1], x2 = x[n*3+2];
    out[idx] = x0 * w[j] + x1 * w[H + j] + x2 * w[2*H + j];
}

#define BM 64
#define BN 64
#define BK 16
// C[M,Ncols] = A[M,K] @ B[K,Ncols], fp32, 64x64 tile, 256 thr, 4x4 microtile
__global__ __launch_bounds__(256) void gemm_fp32(const float* __restrict__ A,
                                                 const float* __restrict__ B,
                                                 float* __restrict__ C,
                                                 int M, int K, int Ncols) {
    __shared__ float As[BK][BM + 1];
    __shared__ float Bs[BK][BN + 1];
    int tid = threadIdx.x;
    int tx = tid & 15, ty = tid >> 4;
    int row0 = blockIdx.x * BM, col0 = blockIdx.y * BN;
    float acc[4][4] = {};
    for (int k0 = 0; k0 < K; k0 += BK) {
        for (int i = tid; i < BM * BK; i += 256) {
            int r = i >> 4, c = i & 15;           // BK = 16
            int gr = row0 + r;
            As[c][r] = (gr < M) ? A[(size_t)gr * K + k0 + c] : 0.f;
        }
        for (int i = tid; i < BK * BN; i += 256) {
            int r = i >> 6, c = i & 63;           // BN = 64
            Bs[r][c] = B[(size_t)(k0 + r) * Ncols + col0 + c];
        }
        __syncthreads();
        #pragma unroll
        for (int kk = 0; kk < BK; ++kk) {
            float a[4], b[4];
            #pragma unroll
            for (int i = 0; i < 4; i++) a[i] = As[kk][ty*4 + i];
            #pragma unroll
            for (int j = 0; j < 4; j++) b[j] = Bs[kk][tx*4 + j];
            #pragma unroll
            for (int i = 0; i < 4; i++)
                #pragma unroll
                for (int j = 0; j < 4; j++) acc[i][j] += a[i] * b[j];
        }
        __syncthreads();
    }
    for (int i = 0; i < 4; i++) {
        int gr = row0 + ty*4 + i;
        if (gr >= M) continue;
        float* cp = C + (size_t)gr * Ncols + col0 + tx*4;
        for (int j = 0; j < 4; j++) cp[j] = acc[i][j];
    }
}

// ---------------- GCN aggregation ----------------
// out[n] = h[n] * dinv[n]^2   (self-loop term; also initializes out)
__global__ void gcn_self(const float* __restrict__ h, const float* __restrict__ dinv,
                         float* __restrict__ out) {
    int idx = blockIdx.x * blockDim.x + threadIdx.x;   // over N * (H/4)
    if (idx >= N_NODES * (H/4)) return;
    int n = idx / (H/4);
    float d = dinv[n];
    float c = d * d;
    float4 v = ((const float4*)h)[idx];
    float4 o; o.x = v.x*c; o.y = v.y*c; o.z = v.z*c; o.w = v.w*c;
    ((float4*)out)[idx] = o;
}

// one block (192 threads = 192 float4) per real edge
__global__ void gcn_edge(const int* __restrict__ src, const int* __restrict__ dst,
                         const float* __restrict__ h, const float* __restrict__ dinv,
                         float* __restrict__ out) {
    int e = blockIdx.x;
    int s = clampi(src[e], N_NODES), d = clampi(dst[e], N_NODES);
    float c = dinv[s] * dinv[d];
    int t = threadIdx.x;   // 0..191
    float4 v = ((const float4*)(h + (size_t)s * H))[t];
    float* op = out + (size_t)d * H + t*4;
    atomicAdd(op + 0, v.x * c);
    atomicAdd(op + 1, v.y * c);
    atomicAdd(op + 2, v.z * c);
    atomicAdd(op + 3, v.w * c);
}

__global__ void bias_act(float* __restrict__ p, const float* __restrict__ b, int relu) {
    int idx = blockIdx.x * blockDim.x + threadIdx.x;
    if (idx >= N_NODES * H) return;
    float v = p[idx] + b[idx % H];
    if (relu) v = fmaxf(v, 0.f);
    p[idx] = v;
}

// ---------------- GAT ----------------
__global__ void gat_alpha(const float* __restrict__ h, const float* __restrict__ as,
                          const float* __restrict__ ad, float* __restrict__ alpha_s,
                          float* __restrict__ alpha_d) {
    int idx = blockIdx.x * blockDim.x + threadIdx.x;
    if (idx >= N_NODES * NH) return;
    int n = idx / NH, hh = idx % NH;
    const float* hp  = h  + (size_t)n * H + hh * HD;
    const float* asp = as + hh * HD;
    const float* adp = ad + hh * HD;
    float ss = 0.f, sd = 0.f;
    for (int k = 0; k < HD; k++) { float v = hp[k]; ss += v * asp[k]; sd += v * adp[k]; }
    alpha_s[idx] = ss; alpha_d[idx] = sd;
}

__device__ inline unsigned enc_f(float v) {
    unsigned u = __float_as_uint(v);
    return (u & 0x80000000u) ? ~u : (u | 0x80000000u);
}
__device__ inline float dec_f(unsigned u) {
    u = (u & 0x80000000u) ? (u ^ 0x80000000u) : ~u;
    return __uint_as_float(u);
}

__global__ void gat_edge_logit(const int* __restrict__ src, const int* __restrict__ dst,
                               const float* __restrict__ alpha_s, const float* __restrict__ alpha_d,
                               float* __restrict__ elog, unsigned* __restrict__ menc) {
    int idx = blockIdx.x * blockDim.x + threadIdx.x;
    if (idx >= EP * NH) return;
    int e = idx / NH, hh = idx % NH;
    int s = (e < N_EDGES) ? clampi(src[e], N_NODES) : (e - N_EDGES);
    int d = (e < N_EDGES) ? clampi(dst[e], N_NODES) : (e - N_EDGES);
    float v = alpha_s[s*NH + hh] + alpha_d[d*NH + hh];
    v = (v > 0.f) ? v : 0.2f * v;      // LeakyReLU(0.2)
    elog[idx] = v;
    atomicMax(&menc[d*NH + hh], enc_f(v));
}

__global__ void m_decode(unsigned* m, int n) {
    int i = blockIdx.x * blockDim.x + threadIdx.x;
    if (i < n) ((float*)m)[i] = dec_f(m[i]);
}

__global__ void gat_exp(const int* __restrict__ dst, const float* __restrict__ m,
                        float* __restrict__ elog, float* __restrict__ ssum) {
    int idx = blockIdx.x * blockDim.x + threadIdx.x;
    if (idx >= EP * NH) return;
    int e = idx / NH, hh = idx % NH;
    int d = (e < N_EDGES) ? clampi(dst[e], N_NODES) : (e - N_EDGES);
    float ex = expf(elog[idx] - m[d*NH + hh]);
    elog[idx] = ex;
    atomicAdd(&ssum[d*NH + hh], ex);
}

// one block (192 threads) per edge; head = t/16 (16 float4 per head)
__global__ void gat_agg(const int* __restrict__ src, const int* __restrict__ dst,
                        const float* __restrict__ h, const float* __restrict__ ex,
                        const float* __restrict__ ssum, float* __restrict__ out) {
    int e = blockIdx.x;
    int s = (e < N_EDGES) ? clampi(src[e], N_NODES) : (e - N_EDGES);
    int d = (e < N_EDGES) ? clampi(dst[e], N_NODES) : (e - N_EDGES);
    int t = threadIdx.x;    // 0..191
    int hh = t >> 4;
    float coef = ex[e*NH + hh] / ssum[d*NH + hh];
    float4 v = ((const float4*)(h + (size_t)s * H))[t];
    float* op = out + (size_t)d * H + t*4;
    atomicAdd(op + 0, v.x * coef);
    atomicAdd(op + 1, v.y * coef);
    atomicAdd(op + 2, v.z * coef);
    atomicAdd(op + 3, v.w * coef);
}

// ---------------- pooling + classifier ----------------
__global__ void pool_cnt(const int* __restrict__ batch, float* cnt) {
    int n = blockIdx.x * blockDim.x + threadIdx.x;
    if (n < N_NODES) atomicAdd(&cnt[clampi(batch[n], NG)], 1.0f);
}

__global__ void pool_sum(const int* __restrict__ batch, const float* __restrict__ h,
                         float* __restrict__ pool) {
    int n = blockIdx.x;
    int g = clampi(batch[n], NG);
    int t = threadIdx.x;   // 0..191
    float4 v = ((const float4*)(h + (size_t)n * H))[t];
    float* op = pool + (size_t)g * H + t*4;
    atomicAdd(op + 0, v.x); atomicAdd(op + 1, v.y);
    atomicAdd(op + 2, v.z); atomicAdd(op + 3, v.w);
}

__global__ void pool_div(float* pool, const float* cnt) {
    int idx = blockIdx.x * blockDim.x + threadIdx.x;
    if (idx >= NG * H) return;
    int g = idx / H;
    pool[idx] /= fmaxf(cnt[g], 1.0f);
}

__global__ void mlp1(const float* __restrict__ g, const float* __restrict__ w,
                     const float* __restrict__ b, float* __restrict__ z) {
    int idx = blockIdx.x * blockDim.x + threadIdx.x;
    if (idx >= NG * H2) return;
    int gg = idx / H2, j = idx % H2;
    const float* gp = g + (size_t)gg * H;
    float acc = b[j];
    for (int k = 0; k < H; k++) acc += gp[k] * w[(size_t)k * H2 + j];
    z[idx] = fmaxf(acc, 0.f);
}

__global__ void mlp2(const float* __restrict__ z, const float* __restrict__ w,
                     const float* __restrict__ b, float* __restrict__ out) {
    int idx = blockIdx.x * blockDim.x + threadIdx.x;
    if (idx >= NG * NC) return;
    int gg = idx / NC, c = idx % NC;
    const float* zp = z + (size_t)gg * H2;
    float acc = b[c];
    for (int k = 0; k < H2; k++) acc += zp[k] * w[(size_t)k * NC + c];
    out[idx] = acc;
}

// ---------------- launch ----------------
extern "C" void kernel_launch(void* const* d_in, const int* in_sizes, int n_in,
                              void* d_out, int out_size, void* d_ws, size_t ws_size,
                              hipStream_t stream) {
    (void)d_ws; (void)ws_size;
    const float* x     = (const float*)d_in[0];
    const int*   ei    = (const int*)d_in[1];
    const int*   batch = (const int*)d_in[2];
    const float* w1  = (const float*)d_in[3];  const float* b1  = (const float*)d_in[4];
    const float* w2  = (const float*)d_in[5];  const float* b2  = (const float*)d_in[6];
    const float* w3  = (const float*)d_in[7];  const float* b3  = (const float*)d_in[8];
    const float* wg1 = (const float*)d_in[9];  const float* as1 = (const float*)d_in[10];
    const float* ad1 = (const float*)d_in[11]; const float* bg1 = (const float*)d_in[12];
    const float* wg2 = (const float*)d_in[13]; const float* as2 = (const float*)d_in[14];
    const float* ad2 = (const float*)d_in[15]; const float* bg2 = (const float*)d_in[16];
    const float* wc1 = (const float*)d_in[17]; const float* bc1 = (const float*)d_in[18];
    const float* wc2 = (const float*)d_in[19]; const float* bc2 = (const float*)d_in[20];

    const int* srcp = ei;            // edge_index[0]
    const int* dstp = ei + N_EDGES;  // edge_index[1]

    // resolve static device buffers (host-side symbol lookup; capture-safe)
    float *bufA, *bufB, *dinv, *aS, *aD, *sb, *exb, *pool, *cnt, *zb;
    unsigned* mb;
    hipGetSymbolAddress((void**)&bufA, HIP_SYMBOL(g_bufA));
    hipGetSymbolAddress((void**)&bufB, HIP_SYMBOL(g_bufB));
    hipGetSymbolAddress((void**)&dinv, HIP_SYMBOL(g_dinv));
    hipGetSymbolAddress((void**)&aS,   HIP_SYMBOL(g_aS));
    hipGetSymbolAddress((void**)&aD,   HIP_SYMBOL(g_aD));
    hipGetSymbolAddress((void**)&mb,   HIP_SYMBOL(g_mb));
    hipGetSymbolAddress((void**)&sb,   HIP_SYMBOL(g_sb));
    hipGetSymbolAddress((void**)&exb,  HIP_SYMBOL(g_exb));
    hipGetSymbolAddress((void**)&pool, HIP_SYMBOL(g_pool));
    hipGetSymbolAddress((void**)&cnt,  HIP_SYMBOL(g_cnt));
    hipGetSymbolAddress((void**)&zb,   HIP_SYMBOL(g_zb));

    auto cdiv = [](int a, int b) { return (a + b - 1) / b; };
    dim3 ggrid(cdiv(N_NODES, BM), H / BN);

    // degree + rsqrt (self-loop counted by init to 1.0)
    fill_f32<<<cdiv(N_NODES,256),256,0,stream>>>(dinv, N_NODES, 1.0f);
    edge_deg<<<cdiv(N_EDGES,256),256,0,stream>>>(dstp, dinv);
    rsqrt_inplace<<<cdiv(N_NODES,256),256,0,stream>>>(dinv, N_NODES);

    // ---- GCN1 ----
    gemm_k3<<<cdiv(N_NODES*H,256),256,0,stream>>>(x, w1, bufA);
    gcn_self<<<cdiv(N_NODES*(H/4),256),256,0,stream>>>(bufA, dinv, bufB);
    gcn_edge<<<N_EDGES,192,0,stream>>>(srcp, dstp, bufA, dinv, bufB);
    bias_act<<<cdiv(N_NODES*H,256),256,0,stream>>>(bufB, b1, 1);

    // ---- GCN2 ----
    gemm_fp32<<<ggrid,256,0,stream>>>(bufB, w2, bufA, N_NODES, H, H);
    gcn_self<<<cdiv(N_NODES*(H/4),256),256,0,stream>>>(bufA, dinv, bufB);
    gcn_edge<<<N_EDGES,192,0,stream>>>(srcp, dstp, bufA, dinv, bufB);
    bias_act<<<cdiv(N_NODES*H,256),256,0,stream>>>(bufB, b2, 1);

    // ---- GCN3 ----
    gemm_fp32<<<ggrid,256,0,stream>>>(bufB, w3, bufA, N_NODES, H, H);
    gcn_self<<<cdiv(N_NODES*(H/4),256),256,0,stream>>>(bufA, dinv, bufB);
    gcn_edge<<<N_EDGES,192,0,stream>>>(srcp, dstp, bufA, dinv, bufB);
    bias_act<<<cdiv(N_NODES*H,256),256,0,stream>>>(bufB, b3, 1);

    // ---- GAT1 ----
    gemm_fp32<<<ggrid,256,0,stream>>>(bufB, wg1, bufA, N_NODES, H, H);
    gat_alpha<<<cdiv(N_NODES*NH,256),256,0,stream>>>(bufA, as1, ad1, aS, aD);
    fill_u32<<<cdiv(N_NODES*NH,256),256,0,stream>>>(mb, N_NODES*NH, 0u);
    gat_edge_logit<<<cdiv(EP*NH,256),256,0,stream>>>(srcp, dstp, aS, aD, exb, mb);
    m_decode<<<cdiv(N_NODES*NH,256),256,0,stream>>>(mb, N_NODES*NH);
    fill_f32<<<cdiv(N_NODES*NH,256),256,0,stream>>>(sb, N_NODES*NH, 0.f);
    gat_exp<<<cdiv(EP*NH,256),256,0,stream>>>(dstp, (const float*)mb, exb, sb);
    fill_f32<<<cdiv(N_NODES*H,256),256,0,stream>>>(bufB, N_NODES*H, 0.f);
    gat_agg<<<EP,192,0,stream>>>(srcp, dstp, bufA, exb, sb, bufB);
    bias_act<<<cdiv(N_NODES*H,256),256,0,stream>>>(bufB, bg1, 1);

    // ---- GAT2 (no relu) ----
    gemm_fp32<<<ggrid,256,0,stream>>>(bufB, wg2, bufA, N_NODES, H, H);
    gat_alpha<<<cdiv(N_NODES*NH,256),256,0,stream>>>(bufA, as2, ad2, aS, aD);
    fill_u32<<<cdiv(N_NODES*NH,256),256,0,stream>>>(mb, N_NODES*NH, 0u);
    gat_edge_logit<<<cdiv(EP*NH,256),256,0,stream>>>(srcp, dstp, aS, aD, exb, mb);
    m_decode<<<cdiv(N_NODES*NH,256),256,0,stream>>>(mb, N_NODES*NH);
    fill_f32<<<cdiv(N_NODES*NH,256),256,0,stream>>>(sb, N_NODES*NH, 0.f);
    gat_exp<<<cdiv(EP*NH,256),256,0,stream>>>(dstp, (const float*)mb, exb, sb);
    fill_f32<<<cdiv(N_NODES*H,256),256,0,stream>>>(bufB, N_NODES*H, 0.f);
    gat_agg<<<EP,192,0,stream>>>(srcp, dstp, bufA, exb, sb, bufB);
    bias_act<<<cdiv(N_NODES*H,256),256,0,stream>>>(bufB, bg2, 0);

    // ---- pool + classifier ----
    fill_f32<<<cdiv(NG*H,256),256,0,stream>>>(pool, NG*H, 0.f);
    fill_f32<<<1,64,0,stream>>>(cnt, NG, 0.f);
    pool_cnt<<<cdiv(N_NODES,256),256,0,stream>>>(batch, cnt);
    pool_sum<<<N_NODES,192,0,stream>>>(batch, bufB, pool);
    pool_div<<<cdiv(NG*H,256),256,0,stream>>>(pool, cnt);
    mlp1<<<cdiv(NG*H2,256),256,0,stream>>>(pool, wc1, bc1, zb);
    mlp2<<<cdiv(NG*NC,64),64,0,stream>>>(zb, wc2, bc2, (float*)d_out);
}

// Round 4
// 3018.163 us; speedup vs baseline: 4.6122x; 4.6122x over previous
//
#include <hip/hip_runtime.h>
#include <math.h>

#define N_NODES 50000
#define N_EDGES 100000
#define H 768
#define NH 12
#define HD 64
#define NG 64
#define NC 10
#define H2 384

typedef __attribute__((ext_vector_type(8))) short          bfrag;   // 8 bf16 (4 VGPR)
typedef __attribute__((ext_vector_type(8))) unsigned short u16v8;   // 16B chunk
typedef __attribute__((ext_vector_type(4))) float          ffrag;   // MFMA acc

// ---------------- static device scratch ----------------
__device__ float          g_bufA[(size_t)N_NODES * H];
__device__ float          g_bufB[(size_t)N_NODES * H];
__device__ unsigned short g_ah[(size_t)N_NODES * H];   // activation hi bf16
__device__ unsigned short g_al[(size_t)N_NODES * H];   // activation lo bf16
__device__ unsigned short g_wh[H * H];                 // weight^T hi bf16 [N][K]
__device__ unsigned short g_wl[H * H];                 // weight^T lo bf16
__device__ float          g_dinv[N_NODES];
__device__ int            g_degi[N_NODES];
__device__ int            g_cursor[N_NODES];
__device__ int            g_rowptr[N_NODES + 1];
__device__ int            g_csrsrc[N_EDGES];
__device__ float          g_aS[(size_t)N_NODES * NH];
__device__ float          g_aD[(size_t)N_NODES * NH];
__device__ float          g_pool[NG * H];
__device__ float          g_zb[NG * H2];

__device__ inline int clampi(int v, int hi) { return (v < 0) ? 0 : (v >= hi ? hi - 1 : v); }

__device__ inline unsigned short bf16rn(float f) {
    unsigned u = __float_as_uint(f);
    unsigned r = u + 0x7fffu + ((u >> 16) & 1u);   // RNE; inputs finite
    return (unsigned short)(r >> 16);
}
__device__ inline float bf16f(unsigned short h) { return __uint_as_float((unsigned)h << 16); }

// ---------------- CSR build ----------------
__global__ void fill_i32(int* p, int n, int v) {
    int i = blockIdx.x * blockDim.x + threadIdx.x;
    if (i < n) p[i] = v;
}

__global__ void count_deg(const int* __restrict__ dst, int* __restrict__ degi) {
    int e = blockIdx.x * blockDim.x + threadIdx.x;
    if (e < N_EDGES) atomicAdd(&degi[clampi(dst[e], N_NODES)], 1);
}

__global__ void dinv_k(const int* __restrict__ degi, float* __restrict__ dinv) {
    int i = blockIdx.x * blockDim.x + threadIdx.x;
    if (i < N_NODES) dinv[i] = rsqrtf((float)degi[i] + 1.0f);   // +1 = self-loop
}

__global__ __launch_bounds__(1024) void scan_rowptr(const int* __restrict__ degi,
                                                    int* __restrict__ rowptr,
                                                    int* __restrict__ cursor) {
    __shared__ int buf[1024];
    __shared__ int carry;
    int tid = threadIdx.x;
    if (tid == 0) carry = 0;
    __syncthreads();
    for (int base = 0; base < N_NODES; base += 1024) {
        int idx = base + tid;
        int v = (idx < N_NODES) ? degi[idx] : 0;
        buf[tid] = v;
        __syncthreads();
        for (int off = 1; off < 1024; off <<= 1) {
            int t = (tid >= off) ? buf[tid - off] : 0;
            __syncthreads();
            buf[tid] += t;
            __syncthreads();
        }
        if (idx < N_NODES) {
            int excl = buf[tid] - v + carry;
            rowptr[idx] = excl;
            cursor[idx] = excl;
        }
        int total = buf[1023];
        __syncthreads();
        if (tid == 0) carry += total;
        __syncthreads();
    }
    if (tid == 0) rowptr[N_NODES] = carry;
}

__global__ void bin_edges(const int* __restrict__ src, const int* __restrict__ dst,
                          int* __restrict__ cursor, int* __restrict__ csrsrc) {
    int e = blockIdx.x * blockDim.x + threadIdx.x;
    if (e >= N_EDGES) return;
    int d = clampi(dst[e], N_NODES);
    int pos = atomicAdd(&cursor[d], 1);
    if (pos >= 0 && pos < N_EDGES) csrsrc[pos] = clampi(src[e], N_NODES);
}

// ---------------- GEMM: x@w1 (K=3) ----------------
__global__ void gemm_k3(const float* __restrict__ x, const float* __restrict__ w,
                        float* __restrict__ out) {
    int idx = blockIdx.x * blockDim.x + threadIdx.x;
    if (idx >= N_NODES * H) return;
    int n = idx / H, j = idx % H;
    float x0 = x[n*3], x1 = x[n*3+1], x2 = x[n*3+2];
    out[idx] = x0 * w[j] + x1 * w[H + j] + x2 * w[2*H + j];
}

// ---------------- bf16 split passes ----------------
// activations: [M][K] fp32 -> hi/lo bf16 same layout
__global__ void split_act(const float* __restrict__ in, unsigned short* __restrict__ hi,
                          unsigned short* __restrict__ lo) {
    int i = blockIdx.x * blockDim.x + threadIdx.x;   // over N*H/4
    if (i >= N_NODES * (H / 4)) return;
    float4 v = ((const float4*)in)[i];
    ushort4 h4, l4;
    h4.x = bf16rn(v.x); l4.x = bf16rn(v.x - bf16f(h4.x));
    h4.y = bf16rn(v.y); l4.y = bf16rn(v.y - bf16f(h4.y));
    h4.z = bf16rn(v.z); l4.z = bf16rn(v.z - bf16f(h4.z));
    h4.w = bf16rn(v.w); l4.w = bf16rn(v.w - bf16f(h4.w));
    ((ushort4*)hi)[i] = h4;
    ((ushort4*)lo)[i] = l4;
}

// weights: w[K][N] fp32 -> transposed hi/lo bf16 [N][K]
__global__ void split_wT(const float* __restrict__ w, unsigned short* __restrict__ hi,
                         unsigned short* __restrict__ lo) {
    int idx = blockIdx.x * blockDim.x + threadIdx.x;   // over H*H
    if (idx >= H * H) return;
    int n = idx % H, k = idx / H;                      // read coalesced in n
    float v = w[(size_t)k * H + n];
    unsigned short h = bf16rn(v);
    hi[(size_t)n * H + k] = h;
    lo[(size_t)n * H + k] = bf16rn(v - bf16f(h));
}

// ---------------- bf16x3 MFMA GEMM ----------------
// C[M,768] = A[M,768] @ W  where A,W pre-split to bf16 hi/lo; W stored transposed [N][K].
// 128x128 tile, 256 threads (4 waves), each wave 64x64 via 4x4 of 16x16x32 MFMA.
#define LDA 40   // padded K-stride (ushorts) for LDS tiles (32 data + 8 pad)
__global__ __launch_bounds__(256) void gemm_bf16x3(const unsigned short* __restrict__ ah,
                                                   const unsigned short* __restrict__ al,
                                                   const unsigned short* __restrict__ bth,
                                                   const unsigned short* __restrict__ btl,
                                                   float* __restrict__ C, int M) {
    __shared__ unsigned short sAh[128 * LDA], sAl[128 * LDA];
    __shared__ unsigned short sBh[128 * LDA], sBl[128 * LDA];
    int tid = threadIdx.x;
    int wave = tid >> 6, lane = tid & 63;
    int quad = lane >> 4, l16 = lane & 15;
    int row0 = blockIdx.x * 128, col0 = blockIdx.y * 128;
    int wr = (wave >> 1) * 64, wc = (wave & 1) * 64;

    ffrag acc[4][4];
    #pragma unroll
    for (int i = 0; i < 4; i++)
        #pragma unroll
        for (int j = 0; j < 4; j++) { ffrag z = {0.f, 0.f, 0.f, 0.f}; acc[i][j] = z; }

    for (int k0 = 0; k0 < H; k0 += 32) {
        // stage A tile: 128 rows x 32 k, as 16B chunks (512 total, 2/thread)
        for (int i = tid; i < 512; i += 256) {
            int r = i >> 2, kq = (i & 3) << 3;
            int gr = row0 + r;
            u16v8 vh = 0, vl = 0;
            if (gr < M) {
                vh = *(const u16v8*)(ah + (size_t)gr * H + k0 + kq);
                vl = *(const u16v8*)(al + (size_t)gr * H + k0 + kq);
            }
            *(u16v8*)(&sAh[r * LDA + kq]) = vh;
            *(u16v8*)(&sAl[r * LDA + kq]) = vl;
        }
        // stage B^T tile: 128 cols x 32 k
        for (int i = tid; i < 512; i += 256) {
            int c = i >> 2, kq = (i & 3) << 3;
            u16v8 vh = *(const u16v8*)(bth + (size_t)(col0 + c) * H + k0 + kq);
            u16v8 vl = *(const u16v8*)(btl + (size_t)(col0 + c) * H + k0 + kq);
            *(u16v8*)(&sBh[c * LDA + kq]) = vh;
            *(u16v8*)(&sBl[c * LDA + kq]) = vl;
        }
        __syncthreads();

        bfrag fah[4], fal[4], fbh[4], fbl[4];
        #pragma unroll
        for (int i = 0; i < 4; i++) {
            int r = wr + i * 16 + l16;
            fah[i] = *reinterpret_cast<const bfrag*>(&sAh[r * LDA + quad * 8]);
            fal[i] = *reinterpret_cast<const bfrag*>(&sAl[r * LDA + quad * 8]);
        }
        #pragma unroll
        for (int j = 0; j < 4; j++) {
            int c = wc + j * 16 + l16;
            fbh[j] = *reinterpret_cast<const bfrag*>(&sBh[c * LDA + quad * 8]);
            fbl[j] = *reinterpret_cast<const bfrag*>(&sBl[c * LDA + quad * 8]);
        }
        #pragma unroll
        for (int i = 0; i < 4; i++)
            #pragma unroll
            for (int j = 0; j < 4; j++) {
                acc[i][j] = __builtin_amdgcn_mfma_f32_16x16x32_bf16(fah[i], fbh[j], acc[i][j], 0, 0, 0);
                acc[i][j] = __builtin_amdgcn_mfma_f32_16x16x32_bf16(fah[i], fbl[j], acc[i][j], 0, 0, 0);
                acc[i][j] = __builtin_amdgcn_mfma_f32_16x16x32_bf16(fal[i], fbh[j], acc[i][j], 0, 0, 0);
            }
        __syncthreads();
    }

    // epilogue: C/D layout col=lane&15, row=quad*4+reg (m89-verified)
    #pragma unroll
    for (int i = 0; i < 4; i++)
        #pragma unroll
        for (int r = 0; r < 4; r++) {
            int row = row0 + wr + i * 16 + quad * 4 + r;
            if (row >= M) continue;
            #pragma unroll
            for (int j = 0; j < 4; j++)
                C[(size_t)row * H + col0 + wc + j * 16 + l16] = acc[i][j][r];
        }
}

// ---------------- fused GCN gather (self + edges + bias + relu) ----------------
// one block (192 threads, float4 each) per dst node
__global__ void gcn_gather(const int* __restrict__ rowptr, const int* __restrict__ csrsrc,
                           const float* __restrict__ h, const float* __restrict__ dinv,
                           const float* __restrict__ bias, float* __restrict__ out) {
    int d = blockIdx.x;
    int t = threadIdx.x;
    float dd = dinv[d];
    float4 v = ((const float4*)(h + (size_t)d * H))[t];
    float c = dd * dd;
    float4 acc; acc.x = v.x * c; acc.y = v.y * c; acc.z = v.z * c; acc.w = v.w * c;
    int beg = rowptr[d], end = rowptr[d + 1];
    for (int i = beg; i < end; i++) {
        int s = csrsrc[i];
        float cc = dinv[s] * dd;
        float4 u = ((const float4*)(h + (size_t)s * H))[t];
        acc.x += u.x * cc; acc.y += u.y * cc; acc.z += u.z * cc; acc.w += u.w * cc;
    }
    float4 b = ((const float4*)bias)[t];
    acc.x = fmaxf(acc.x + b.x, 0.f); acc.y = fmaxf(acc.y + b.y, 0.f);
    acc.z = fmaxf(acc.z + b.z, 0.f); acc.w = fmaxf(acc.w + b.w, 0.f);
    ((float4*)(out + (size_t)d * H))[t] = acc;
}

// ---------------- GAT ----------------
__global__ void gat_alpha(const float* __restrict__ h, const float* __restrict__ as,
                          const float* __restrict__ ad, float* __restrict__ alpha_s,
                          float* __restrict__ alpha_d) {
    int idx = blockIdx.x * blockDim.x + threadIdx.x;
    if (idx >= N_NODES * NH) return;
    int n = idx / NH, hh = idx % NH;
    const float* hp  = h  + (size_t)n * H + hh * HD;
    const float* asp = as + hh * HD;
    const float* adp = ad + hh * HD;
    float ss = 0.f, sd = 0.f;
    for (int k = 0; k < HD; k++) { float v = hp[k]; ss += v * asp[k]; sd += v * adp[k]; }
    alpha_s[idx] = ss; alpha_d[idx] = sd;
}

__device__ inline float lrelu(float v) { return (v > 0.f) ? v : 0.2f * v; }

// fused softmax + weighted aggregation + bias (+relu); one block per dst node.
// 192 threads: thread t covers float4 #t of the row; its head is t>>4.
__global__ void gat_gather(const int* __restrict__ rowptr, const int* __restrict__ csrsrc,
                           const float* __restrict__ h, const float* __restrict__ aS,
                           const float* __restrict__ aD, const float* __restrict__ bias,
                           float* __restrict__ out, int relu) {
    int d = blockIdx.x;
    int t = threadIdx.x;
    int hh = t >> 4;
    int beg = rowptr[d], end = rowptr[d + 1];
    float adv = aD[d * NH + hh];
    float eself = lrelu(aS[d * NH + hh] + adv);
    // pass 0: max
    float m = eself;
    for (int i = beg; i < end; i++)
        m = fmaxf(m, lrelu(aS[csrsrc[i] * NH + hh] + adv));
    // pass 1: sum of exp
    float ssum = __expf(eself - m);
    for (int i = beg; i < end; i++)
        ssum += __expf(lrelu(aS[csrsrc[i] * NH + hh] + adv) - m);
    float inv = 1.0f / ssum;
    // pass 2: weighted aggregation
    float cself = __expf(eself - m) * inv;
    float4 v = ((const float4*)(h + (size_t)d * H))[t];
    float4 acc; acc.x = v.x * cself; acc.y = v.y * cself; acc.z = v.z * cself; acc.w = v.w * cself;
    for (int i = beg; i < end; i++) {
        int s = csrsrc[i];
        float c = __expf(lrelu(aS[s * NH + hh] + adv) - m) * inv;
        float4 u = ((const float4*)(h + (size_t)s * H))[t];
        acc.x += u.x * c; acc.y += u.y * c; acc.z += u.z * c; acc.w += u.w * c;
    }
    float4 b = ((const float4*)bias)[t];
    acc.x += b.x; acc.y += b.y; acc.z += b.z; acc.w += b.w;
    if (relu) {
        acc.x = fmaxf(acc.x, 0.f); acc.y = fmaxf(acc.y, 0.f);
        acc.z = fmaxf(acc.z, 0.f); acc.w = fmaxf(acc.w, 0.f);
    }
    ((float4*)(out + (size_t)d * H))[t] = acc;
}

// ---------------- pooling (batch is sorted) + classifier ----------------
__device__ inline int lower_bound_i(const int* b, int n, int key) {
    int lo = 0, hi = n;
    while (lo < hi) { int mid = (lo + hi) >> 1; if (b[mid] < key) lo = mid + 1; else hi = mid; }
    return lo;
}

__global__ void pool_graph(const int* __restrict__ batch, const float* __restrict__ h,
                           float* __restrict__ pool) {
    int g = blockIdx.x;   // NG blocks, 192 threads
    int t = threadIdx.x;
    int lo = lower_bound_i(batch, N_NODES, g);
    int hi = lower_bound_i(batch, N_NODES, g + 1);
    float4 a0 = {0,0,0,0}, a1 = {0,0,0,0}, a2 = {0,0,0,0}, a3 = {0,0,0,0};
    int n = lo;
    for (; n + 3 < hi; n += 4) {
        float4 v0 = ((const float4*)(h + (size_t)(n+0) * H))[t];
        float4 v1 = ((const float4*)(h + (size_t)(n+1) * H))[t];
        float4 v2 = ((const float4*)(h + (size_t)(n+2) * H))[t];
        float4 v3 = ((const float4*)(h + (size_t)(n+3) * H))[t];
        a0.x += v0.x; a0.y += v0.y; a0.z += v0.z; a0.w += v0.w;
        a1.x += v1.x; a1.y += v1.y; a1.z += v1.z; a1.w += v1.w;
        a2.x += v2.x; a2.y += v2.y; a2.z += v2.z; a2.w += v2.w;
        a3.x += v3.x; a3.y += v3.y; a3.z += v3.z; a3.w += v3.w;
    }
    for (; n < hi; n++) {
        float4 v = ((const float4*)(h + (size_t)n * H))[t];
        a0.x += v.x; a0.y += v.y; a0.z += v.z; a0.w += v.w;
    }
    float inv = 1.0f / fmaxf((float)(hi - lo), 1.0f);
    float4 o;
    o.x = (a0.x + a1.x + a2.x + a3.x) * inv;
    o.y = (a0.y + a1.y + a2.y + a3.y) * inv;
    o.z = (a0.z + a1.z + a2.z + a3.z) * inv;
    o.w = (a0.w + a1.w + a2.w + a3.w) * inv;
    ((float4*)(pool + (size_t)g * H))[t] = o;
}

__global__ void mlp1(const float* __restrict__ g, const float* __restrict__ w,
                     const float* __restrict__ b, float* __restrict__ z) {
    int idx = blockIdx.x * blockDim.x + threadIdx.x;
    if (idx >= NG * H2) return;
    int gg = idx / H2, j = idx % H2;
    const float* gp = g + (size_t)gg * H;
    float acc = b[j];
    for (int k = 0; k < H; k++) acc += gp[k] * w[(size_t)k * H2 + j];
    z[idx] = fmaxf(acc, 0.f);
}

__global__ void mlp2(const float* __restrict__ z, const float* __restrict__ w,
                     const float* __restrict__ b, float* __restrict__ out) {
    int idx = blockIdx.x * blockDim.x + threadIdx.x;
    if (idx >= NG * NC) return;
    int gg = idx / NC, c = idx % NC;
    const float* zp = z + (size_t)gg * H2;
    float acc = b[c];
    for (int k = 0; k < H2; k++) acc += zp[k] * w[(size_t)k * NC + c];
    out[idx] = acc;
}

// ---------------- launch ----------------
extern "C" void kernel_launch(void* const* d_in, const int* in_sizes, int n_in,
                              void* d_out, int out_size, void* d_ws, size_t ws_size,
                              hipStream_t stream) {
    (void)d_ws; (void)ws_size;
    const float* x     = (const float*)d_in[0];
    const int*   ei    = (const int*)d_in[1];
    const int*   batch = (const int*)d_in[2];
    const float* w1  = (const float*)d_in[3];  const float* b1  = (const float*)d_in[4];
    const float* w2  = (const float*)d_in[5];  const float* b2  = (const float*)d_in[6];
    const float* w3  = (const float*)d_in[7];  const float* b3  = (const float*)d_in[8];
    const float* wg1 = (const float*)d_in[9];  const float* as1 = (const float*)d_in[10];
    const float* ad1 = (const float*)d_in[11]; const float* bg1 = (const float*)d_in[12];
    const float* wg2 = (const float*)d_in[13]; const float* as2 = (const float*)d_in[14];
    const float* ad2 = (const float*)d_in[15]; const float* bg2 = (const float*)d_in[16];
    const float* wc1 = (const float*)d_in[17]; const float* bc1 = (const float*)d_in[18];
    const float* wc2 = (const float*)d_in[19]; const float* bc2 = (const float*)d_in[20];

    const int* srcp = ei;            // edge_index[0]
    const int* dstp = ei + N_EDGES;  // edge_index[1]

    float *bufA, *bufB, *dinv, *aS, *aD, *pool, *zb;
    unsigned short *ah, *al, *wh, *wl;
    int *degi, *cursor, *rowptr, *csrsrc;
    hipGetSymbolAddress((void**)&bufA,   HIP_SYMBOL(g_bufA));
    hipGetSymbolAddress((void**)&bufB,   HIP_SYMBOL(g_bufB));
    hipGetSymbolAddress((void**)&ah,     HIP_SYMBOL(g_ah));
    hipGetSymbolAddress((void**)&al,     HIP_SYMBOL(g_al));
    hipGetSymbolAddress((void**)&wh,     HIP_SYMBOL(g_wh));
    hipGetSymbolAddress((void**)&wl,     HIP_SYMBOL(g_wl));
    hipGetSymbolAddress((void**)&dinv,   HIP_SYMBOL(g_dinv));
    hipGetSymbolAddress((void**)&degi,   HIP_SYMBOL(g_degi));
    hipGetSymbolAddress((void**)&cursor, HIP_SYMBOL(g_cursor));
    hipGetSymbolAddress((void**)&rowptr, HIP_SYMBOL(g_rowptr));
    hipGetSymbolAddress((void**)&csrsrc, HIP_SYMBOL(g_csrsrc));
    hipGetSymbolAddress((void**)&aS,     HIP_SYMBOL(g_aS));
    hipGetSymbolAddress((void**)&aD,     HIP_SYMBOL(g_aD));
    hipGetSymbolAddress((void**)&pool,   HIP_SYMBOL(g_pool));
    hipGetSymbolAddress((void**)&zb,     HIP_SYMBOL(g_zb));

    auto cdiv = [](int a, int b) { return (a + b - 1) / b; };
    dim3 ggrid(cdiv(N_NODES, 128), H / 128);
    int nh4 = N_NODES * (H / 4);

    // ---- CSR build (per call; inputs re-restored each launch) ----
    fill_i32<<<cdiv(N_NODES,256),256,0,stream>>>(degi, N_NODES, 0);
    count_deg<<<cdiv(N_EDGES,256),256,0,stream>>>(dstp, degi);
    dinv_k<<<cdiv(N_NODES,256),256,0,stream>>>(degi, dinv);
    scan_rowptr<<<1,1024,0,stream>>>(degi, rowptr, cursor);
    bin_edges<<<cdiv(N_EDGES,256),256,0,stream>>>(srcp, dstp, cursor, csrsrc);

    // ---- GCN1 (K=3 GEMM stays fp32 vector) ----
    gemm_k3<<<cdiv(N_NODES*H,256),256,0,stream>>>(x, w1, bufA);
    gcn_gather<<<N_NODES,192,0,stream>>>(rowptr, csrsrc, bufA, dinv, b1, bufB);

    // ---- GCN2 ----
    split_act<<<cdiv(nh4,256),256,0,stream>>>(bufB, ah, al);
    split_wT<<<cdiv(H*H,256),256,0,stream>>>(w2, wh, wl);
    gemm_bf16x3<<<ggrid,256,0,stream>>>(ah, al, wh, wl, bufA, N_NODES);
    gcn_gather<<<N_NODES,192,0,stream>>>(rowptr, csrsrc, bufA, dinv, b2, bufB);

    // ---- GCN3 ----
    split_act<<<cdiv(nh4,256),256,0,stream>>>(bufB, ah, al);
    split_wT<<<cdiv(H*H,256),256,0,stream>>>(w3, wh, wl);
    gemm_bf16x3<<<ggrid,256,0,stream>>>(ah, al, wh, wl, bufA, N_NODES);
    gcn_gather<<<N_NODES,192,0,stream>>>(rowptr, csrsrc, bufA, dinv, b3, bufB);

    // ---- GAT1 ----
    split_act<<<cdiv(nh4,256),256,0,stream>>>(bufB, ah, al);
    split_wT<<<cdiv(H*H,256),256,0,stream>>>(wg1, wh, wl);
    gemm_bf16x3<<<ggrid,256,0,stream>>>(ah, al, wh, wl, bufA, N_NODES);
    gat_alpha<<<cdiv(N_NODES*NH,256),256,0,stream>>>(bufA, as1, ad1, aS, aD);
    gat_gather<<<N_NODES,192,0,stream>>>(rowptr, csrsrc, bufA, aS, aD, bg1, bufB, 1);

    // ---- GAT2 (no relu) ----
    split_act<<<cdiv(nh4,256),256,0,stream>>>(bufB, ah, al);
    split_wT<<<cdiv(H*H,256),256,0,stream>>>(wg2, wh, wl);
    gemm_bf16x3<<<ggrid,256,0,stream>>>(ah, al, wh, wl, bufA, N_NODES);
    gat_alpha<<<cdiv(N_NODES*NH,256),256,0,stream>>>(bufA, as2, ad2, aS, aD);
    gat_gather<<<N_NODES,192,0,stream>>>(rowptr, csrsrc, bufA, aS, aD, bg2, bufB, 0);

    // ---- pool + classifier ----
    pool_graph<<<NG,192,0,stream>>>(batch, bufB, pool);
    mlp1<<<cdiv(NG*H2,256),256,0,stream>>>(pool, wc1, bc1, zb);
    mlp2<<<cdiv(NG*NC,64),64,0,stream>>>(zb, wc2, bc2, (float*)d_out);
}

// Round 5
// 2845.458 us; speedup vs baseline: 4.8921x; 1.0607x over previous
//
#include <hip/hip_runtime.h>
#include <math.h>

#define N_NODES 50000
#define N_EDGES 100000
#define H 768
#define NH 12
#define HD 64
#define NG 64
#define NC 10
#define H2 384

typedef __attribute__((ext_vector_type(8))) short          bfrag;   // 8 bf16 (4 VGPR)
typedef __attribute__((ext_vector_type(8))) unsigned short u16v8;   // 16B chunk
typedef __attribute__((ext_vector_type(4))) float          ffrag;   // MFMA acc

// ---------------- static device scratch ----------------
__device__ float          g_bufA[(size_t)N_NODES * H];
__device__ float          g_bufB[(size_t)N_NODES * H];
__device__ unsigned short g_ah[(size_t)N_NODES * H];   // activation hi bf16
__device__ unsigned short g_al[(size_t)N_NODES * H];   // activation lo bf16
__device__ unsigned short g_wh[H * H];                 // weight^T hi bf16 [N][K]
__device__ unsigned short g_wl[H * H];                 // weight^T lo bf16
__device__ float          g_dinv[N_NODES];
__device__ int            g_degi[N_NODES];
__device__ int            g_cursor[N_NODES];
__device__ int            g_rowptr[N_NODES + 1];
__device__ int            g_csrsrc[N_EDGES];
__device__ float          g_aS[(size_t)N_NODES * NH];
__device__ float          g_aD[(size_t)N_NODES * NH];
__device__ float          g_pool[NG * H];
__device__ float          g_zb[NG * H2];

__device__ inline int clampi(int v, int hi) { return (v < 0) ? 0 : (v >= hi ? hi - 1 : v); }

__device__ inline unsigned short bf16rn(float f) {
    unsigned u = __float_as_uint(f);
    unsigned r = u + 0x7fffu + ((u >> 16) & 1u);   // RNE; inputs finite
    return (unsigned short)(r >> 16);
}
__device__ inline float bf16f(unsigned short h) { return __uint_as_float((unsigned)h << 16); }

// ---------------- CSR build ----------------
__global__ void fill_i32(int* p, int n, int v) {
    int i = blockIdx.x * blockDim.x + threadIdx.x;
    if (i < n) p[i] = v;
}

__global__ void count_deg(const int* __restrict__ dst, int* __restrict__ degi) {
    int e = blockIdx.x * blockDim.x + threadIdx.x;
    if (e < N_EDGES) atomicAdd(&degi[clampi(dst[e], N_NODES)], 1);
}

__global__ void dinv_k(const int* __restrict__ degi, float* __restrict__ dinv) {
    int i = blockIdx.x * blockDim.x + threadIdx.x;
    if (i < N_NODES) dinv[i] = rsqrtf((float)degi[i] + 1.0f);   // +1 = self-loop
}

__global__ __launch_bounds__(1024) void scan_rowptr(const int* __restrict__ degi,
                                                    int* __restrict__ rowptr,
                                                    int* __restrict__ cursor) {
    __shared__ int buf[1024];
    __shared__ int carry;
    int tid = threadIdx.x;
    if (tid == 0) carry = 0;
    __syncthreads();
    for (int base = 0; base < N_NODES; base += 1024) {
        int idx = base + tid;
        int v = (idx < N_NODES) ? degi[idx] : 0;
        buf[tid] = v;
        __syncthreads();
        for (int off = 1; off < 1024; off <<= 1) {
            int t = (tid >= off) ? buf[tid - off] : 0;
            __syncthreads();
            buf[tid] += t;
            __syncthreads();
        }
        if (idx < N_NODES) {
            int excl = buf[tid] - v + carry;
            rowptr[idx] = excl;
            cursor[idx] = excl;
        }
        int total = buf[1023];
        __syncthreads();
        if (tid == 0) carry += total;
        __syncthreads();
    }
    if (tid == 0) rowptr[N_NODES] = carry;
}

__global__ void bin_edges(const int* __restrict__ src, const int* __restrict__ dst,
                          int* __restrict__ cursor, int* __restrict__ csrsrc) {
    int e = blockIdx.x * blockDim.x + threadIdx.x;
    if (e >= N_EDGES) return;
    int d = clampi(dst[e], N_NODES);
    int pos = atomicAdd(&cursor[d], 1);
    if (pos >= 0 && pos < N_EDGES) csrsrc[pos] = clampi(src[e], N_NODES);
}

// ---------------- GEMM: x@w1 (K=3) ----------------
__global__ void gemm_k3(const float* __restrict__ x, const float* __restrict__ w,
                        float* __restrict__ out) {
    int idx = blockIdx.x * blockDim.x + threadIdx.x;
    if (idx >= N_NODES * H) return;
    int n = idx / H, j = idx % H;
    float x0 = x[n*3], x1 = x[n*3+1], x2 = x[n*3+2];
    out[idx] = x0 * w[j] + x1 * w[H + j] + x2 * w[2*H + j];
}

// weights: w[K][N] fp32 -> transposed hi/lo bf16 [N][K]
__global__ void split_wT(const float* __restrict__ w, unsigned short* __restrict__ hi,
                         unsigned short* __restrict__ lo) {
    int idx = blockIdx.x * blockDim.x + threadIdx.x;   // over H*H
    if (idx >= H * H) return;
    int n = idx % H, k = idx / H;                      // read coalesced in n
    float v = w[(size_t)k * H + n];
    unsigned short h = bf16rn(v);
    hi[(size_t)n * H + k] = h;
    lo[(size_t)n * H + k] = bf16rn(v - bf16f(h));
}

// ---------------- bf16x3 MFMA GEMM ----------------
// C[M,768] = A[M,768] @ W; A,W pre-split bf16 hi/lo; W transposed [N][K].
// 128x128 tile, 256 threads (4 waves), wave = 64x64 via 4x4 of 16x16x32 MFMA.
// 1-D grid, swizzled so 6 consecutive blocks share one 128-row A strip:
// the strip is HBM-fetched once, the other 5 reads hit L3 (A re-fetch was
// 920 MB/dispatch with the naive 2-D grid — round-4 counter evidence).
#define LDA 40   // padded K-stride (ushorts); fragment reads land 2-way = free
__global__ __launch_bounds__(256) void gemm_bf16x3(const unsigned short* __restrict__ ah,
                                                   const unsigned short* __restrict__ al,
                                                   const unsigned short* __restrict__ bth,
                                                   const unsigned short* __restrict__ btl,
                                                   float* __restrict__ C, int M) {
    __shared__ unsigned short sAh[128 * LDA], sAl[128 * LDA];
    __shared__ unsigned short sBh[128 * LDA], sBl[128 * LDA];
    int tid = threadIdx.x;
    int wave = tid >> 6, lane = tid & 63;
    int quad = lane >> 4, l16 = lane & 15;
    int bx = blockIdx.x / (H / 128);          // row tile (391)
    int by = blockIdx.x % (H / 128);          // col tile (6)
    int row0 = bx * 128, col0 = by * 128;
    int wr = (wave >> 1) * 64, wc = (wave & 1) * 64;

    ffrag acc[4][4];
    #pragma unroll
    for (int i = 0; i < 4; i++)
        #pragma unroll
        for (int j = 0; j < 4; j++) { ffrag z = {0.f, 0.f, 0.f, 0.f}; acc[i][j] = z; }

    for (int k0 = 0; k0 < H; k0 += 32) {
        // stage A tile: 128 rows x 32 k, 16B chunks (512 total, 2/thread)
        for (int i = tid; i < 512; i += 256) {
            int r = i >> 2, kq = (i & 3) << 3;
            int gr = row0 + r;
            u16v8 vh = 0, vl = 0;
            if (gr < M) {
                vh = *(const u16v8*)(ah + (size_t)gr * H + k0 + kq);
                vl = *(const u16v8*)(al + (size_t)gr * H + k0 + kq);
            }
            *(u16v8*)(&sAh[r * LDA + kq]) = vh;
            *(u16v8*)(&sAl[r * LDA + kq]) = vl;
        }
        // stage B^T tile: 128 cols x 32 k
        for (int i = tid; i < 512; i += 256) {
            int c = i >> 2, kq = (i & 3) << 3;
            u16v8 vh = *(const u16v8*)(bth + (size_t)(col0 + c) * H + k0 + kq);
            u16v8 vl = *(const u16v8*)(btl + (size_t)(col0 + c) * H + k0 + kq);
            *(u16v8*)(&sBh[c * LDA + kq]) = vh;
            *(u16v8*)(&sBl[c * LDA + kq]) = vl;
        }
        __syncthreads();

        bfrag fah[4], fal[4], fbh[4], fbl[4];
        #pragma unroll
        for (int i = 0; i < 4; i++) {
            int r = wr + i * 16 + l16;
            fah[i] = *reinterpret_cast<const bfrag*>(&sAh[r * LDA + quad * 8]);
            fal[i] = *reinterpret_cast<const bfrag*>(&sAl[r * LDA + quad * 8]);
        }
        #pragma unroll
        for (int j = 0; j < 4; j++) {
            int c = wc + j * 16 + l16;
            fbh[j] = *reinterpret_cast<const bfrag*>(&sBh[c * LDA + quad * 8]);
            fbl[j] = *reinterpret_cast<const bfrag*>(&sBl[c * LDA + quad * 8]);
        }
        #pragma unroll
        for (int i = 0; i < 4; i++)
            #pragma unroll
            for (int j = 0; j < 4; j++) {
                acc[i][j] = __builtin_amdgcn_mfma_f32_16x16x32_bf16(fah[i], fbh[j], acc[i][j], 0, 0, 0);
                acc[i][j] = __builtin_amdgcn_mfma_f32_16x16x32_bf16(fah[i], fbl[j], acc[i][j], 0, 0, 0);
                acc[i][j] = __builtin_amdgcn_mfma_f32_16x16x32_bf16(fal[i], fbh[j], acc[i][j], 0, 0, 0);
            }
        __syncthreads();
    }

    // epilogue: C/D layout col=lane&15, row=quad*4+reg (m89-verified)
    #pragma unroll
    for (int i = 0; i < 4; i++)
        #pragma unroll
        for (int r = 0; r < 4; r++) {
            int row = row0 + wr + i * 16 + quad * 4 + r;
            if (row >= M) continue;
            #pragma unroll
            for (int j = 0; j < 4; j++)
                C[(size_t)row * H + col0 + wc + j * 16 + l16] = acc[i][j][r];
        }
}

// ---------------- fused GCN gather (self + edges + bias + relu [+ bf16 split]) ----
// one block (192 threads, float4 each) per dst node.
// If hi != null, writes the bf16 hi/lo split (next GEMM's input) instead of fp32.
__global__ void gcn_gather(const int* __restrict__ rowptr, const int* __restrict__ csrsrc,
                           const float* __restrict__ h, const float* __restrict__ dinv,
                           const float* __restrict__ bias,
                           unsigned short* __restrict__ hi, unsigned short* __restrict__ lo) {
    int d = blockIdx.x;
    int t = threadIdx.x;
    float dd = dinv[d];
    float4 v = ((const float4*)(h + (size_t)d * H))[t];
    float c = dd * dd;
    float4 acc; acc.x = v.x * c; acc.y = v.y * c; acc.z = v.z * c; acc.w = v.w * c;
    int beg = rowptr[d], end = rowptr[d + 1];
    for (int i = beg; i < end; i++) {
        int s = csrsrc[i];
        float cc = dinv[s] * dd;
        float4 u = ((const float4*)(h + (size_t)s * H))[t];
        acc.x += u.x * cc; acc.y += u.y * cc; acc.z += u.z * cc; acc.w += u.w * cc;
    }
    float4 b = ((const float4*)bias)[t];
    acc.x = fmaxf(acc.x + b.x, 0.f); acc.y = fmaxf(acc.y + b.y, 0.f);
    acc.z = fmaxf(acc.z + b.z, 0.f); acc.w = fmaxf(acc.w + b.w, 0.f);
    ushort4 h4, l4;
    h4.x = bf16rn(acc.x); l4.x = bf16rn(acc.x - bf16f(h4.x));
    h4.y = bf16rn(acc.y); l4.y = bf16rn(acc.y - bf16f(h4.y));
    h4.z = bf16rn(acc.z); l4.z = bf16rn(acc.z - bf16f(h4.z));
    h4.w = bf16rn(acc.w); l4.w = bf16rn(acc.w - bf16f(h4.w));
    ((ushort4*)(hi + (size_t)d * H))[t] = h4;
    ((ushort4*)(lo + (size_t)d * H))[t] = l4;
}

// ---------------- GAT ----------------
__global__ void gat_alpha(const float* __restrict__ h, const float* __restrict__ as,
                          const float* __restrict__ ad, float* __restrict__ alpha_s,
                          float* __restrict__ alpha_d) {
    int idx = blockIdx.x * blockDim.x + threadIdx.x;
    if (idx >= N_NODES * NH) return;
    int n = idx / NH, hh = idx % NH;
    const float* hp  = h  + (size_t)n * H + hh * HD;
    const float* asp = as + hh * HD;
    const float* adp = ad + hh * HD;
    float ss = 0.f, sd = 0.f;
    for (int k = 0; k < HD; k++) { float v = hp[k]; ss += v * asp[k]; sd += v * adp[k]; }
    alpha_s[idx] = ss; alpha_d[idx] = sd;
}

__device__ inline float lrelu(float v) { return (v > 0.f) ? v : 0.2f * v; }

// fused softmax + weighted aggregation + bias (+relu); one block per dst node.
// 192 threads: thread t covers float4 #t of the row; its head is t>>4.
// If hi != null, writes bf16 hi/lo split; else fp32 to out.
__global__ void gat_gather(const int* __restrict__ rowptr, const int* __restrict__ csrsrc,
                           const float* __restrict__ h, const float* __restrict__ aS,
                           const float* __restrict__ aD, const float* __restrict__ bias,
                           float* __restrict__ out,
                           unsigned short* __restrict__ hi, unsigned short* __restrict__ lo,
                           int relu) {
    int d = blockIdx.x;
    int t = threadIdx.x;
    int hh = t >> 4;
    int beg = rowptr[d], end = rowptr[d + 1];
    float adv = aD[d * NH + hh];
    float eself = lrelu(aS[d * NH + hh] + adv);
    float m = eself;
    for (int i = beg; i < end; i++)
        m = fmaxf(m, lrelu(aS[csrsrc[i] * NH + hh] + adv));
    float ssum = __expf(eself - m);
    for (int i = beg; i < end; i++)
        ssum += __expf(lrelu(aS[csrsrc[i] * NH + hh] + adv) - m);
    float inv = 1.0f / ssum;
    float cself = __expf(eself - m) * inv;
    float4 v = ((const float4*)(h + (size_t)d * H))[t];
    float4 acc; acc.x = v.x * cself; acc.y = v.y * cself; acc.z = v.z * cself; acc.w = v.w * cself;
    for (int i = beg; i < end; i++) {
        int s = csrsrc[i];
        float c = __expf(lrelu(aS[s * NH + hh] + adv) - m) * inv;
        float4 u = ((const float4*)(h + (size_t)s * H))[t];
        acc.x += u.x * c; acc.y += u.y * c; acc.z += u.z * c; acc.w += u.w * c;
    }
    float4 b = ((const float4*)bias)[t];
    acc.x += b.x; acc.y += b.y; acc.z += b.z; acc.w += b.w;
    if (relu) {
        acc.x = fmaxf(acc.x, 0.f); acc.y = fmaxf(acc.y, 0.f);
        acc.z = fmaxf(acc.z, 0.f); acc.w = fmaxf(acc.w, 0.f);
    }
    if (hi) {
        ushort4 h4, l4;
        h4.x = bf16rn(acc.x); l4.x = bf16rn(acc.x - bf16f(h4.x));
        h4.y = bf16rn(acc.y); l4.y = bf16rn(acc.y - bf16f(h4.y));
        h4.z = bf16rn(acc.z); l4.z = bf16rn(acc.z - bf16f(h4.z));
        h4.w = bf16rn(acc.w); l4.w = bf16rn(acc.w - bf16f(h4.w));
        ((ushort4*)(hi + (size_t)d * H))[t] = h4;
        ((ushort4*)(lo + (size_t)d * H))[t] = l4;
    } else {
        ((float4*)(out + (size_t)d * H))[t] = acc;
    }
}

// ---------------- pooling (batch is sorted) + classifier ----------------
__device__ inline int lower_bound_i(const int* b, int n, int key) {
    int lo = 0, hi = n;
    while (lo < hi) { int mid = (lo + hi) >> 1; if (b[mid] < key) lo = mid + 1; else hi = mid; }
    return lo;
}

__global__ void pool_graph(const int* __restrict__ batch, const float* __restrict__ h,
                           float* __restrict__ pool) {
    int g = blockIdx.x;   // NG blocks, 192 threads
    int t = threadIdx.x;
    int lo = lower_bound_i(batch, N_NODES, g);
    int hi = lower_bound_i(batch, N_NODES, g + 1);
    float4 a0 = {0,0,0,0}, a1 = {0,0,0,0}, a2 = {0,0,0,0}, a3 = {0,0,0,0};
    int n = lo;
    for (; n + 3 < hi; n += 4) {
        float4 v0 = ((const float4*)(h + (size_t)(n+0) * H))[t];
        float4 v1 = ((const float4*)(h + (size_t)(n+1) * H))[t];
        float4 v2 = ((const float4*)(h + (size_t)(n+2) * H))[t];
        float4 v3 = ((const float4*)(h + (size_t)(n+3) * H))[t];
        a0.x += v0.x; a0.y += v0.y; a0.z += v0.z; a0.w += v0.w;
        a1.x += v1.x; a1.y += v1.y; a1.z += v1.z; a1.w += v1.w;
        a2.x += v2.x; a2.y += v2.y; a2.z += v2.z; a2.w += v2.w;
        a3.x += v3.x; a3.y += v3.y; a3.z += v3.z; a3.w += v3.w;
    }
    for (; n < hi; n++) {
        float4 v = ((const float4*)(h + (size_t)n * H))[t];
        a0.x += v.x; a0.y += v.y; a0.z += v.z; a0.w += v.w;
    }
    float inv = 1.0f / fmaxf((float)(hi - lo), 1.0f);
    float4 o;
    o.x = (a0.x + a1.x + a2.x + a3.x) * inv;
    o.y = (a0.y + a1.y + a2.y + a3.y) * inv;
    o.z = (a0.z + a1.z + a2.z + a3.z) * inv;
    o.w = (a0.w + a1.w + a2.w + a3.w) * inv;
    ((float4*)(pool + (size_t)g * H))[t] = o;
}

__global__ void mlp1(const float* __restrict__ g, const float* __restrict__ w,
                     const float* __restrict__ b, float* __restrict__ z) {
    int idx = blockIdx.x * blockDim.x + threadIdx.x;
    if (idx >= NG * H2) return;
    int gg = idx / H2, j = idx % H2;
    const float* gp = g + (size_t)gg * H;
    float acc = b[j];
    for (int k = 0; k < H; k++) acc += gp[k] * w[(size_t)k * H2 + j];
    z[idx] = fmaxf(acc, 0.f);
}

__global__ void mlp2(const float* __restrict__ z, const float* __restrict__ w,
                     const float* __restrict__ b, float* __restrict__ out) {
    int idx = blockIdx.x * blockDim.x + threadIdx.x;
    if (idx >= NG * NC) return;
    int gg = idx / NC, c = idx % NC;
    const float* zp = z + (size_t)gg * H2;
    float acc = b[c];
    for (int k = 0; k < H2; k++) acc += zp[k] * w[(size_t)k * NC + c];
    out[idx] = acc;
}

// ---------------- launch ----------------
extern "C" void kernel_launch(void* const* d_in, const int* in_sizes, int n_in,
                              void* d_out, int out_size, void* d_ws, size_t ws_size,
                              hipStream_t stream) {
    (void)d_ws; (void)ws_size;
    const float* x     = (const float*)d_in[0];
    const int*   ei    = (const int*)d_in[1];
    const int*   batch = (const int*)d_in[2];
    const float* w1  = (const float*)d_in[3];  const float* b1  = (const float*)d_in[4];
    const float* w2  = (const float*)d_in[5];  const float* b2  = (const float*)d_in[6];
    const float* w3  = (const float*)d_in[7];  const float* b3  = (const float*)d_in[8];
    const float* wg1 = (const float*)d_in[9];  const float* as1 = (const float*)d_in[10];
    const float* ad1 = (const float*)d_in[11]; const float* bg1 = (const float*)d_in[12];
    const float* wg2 = (const float*)d_in[13]; const float* as2 = (const float*)d_in[14];
    const float* ad2 = (const float*)d_in[15]; const float* bg2 = (const float*)d_in[16];
    const float* wc1 = (const float*)d_in[17]; const float* bc1 = (const float*)d_in[18];
    const float* wc2 = (const float*)d_in[19]; const float* bc2 = (const float*)d_in[20];

    const int* srcp = ei;            // edge_index[0]
    const int* dstp = ei + N_EDGES;  // edge_index[1]

    float *bufA, *bufB, *dinv, *aS, *aD, *pool, *zb;
    unsigned short *ah, *al, *wh, *wl;
    int *degi, *cursor, *rowptr, *csrsrc;
    hipGetSymbolAddress((void**)&bufA,   HIP_SYMBOL(g_bufA));
    hipGetSymbolAddress((void**)&bufB,   HIP_SYMBOL(g_bufB));
    hipGetSymbolAddress((void**)&ah,     HIP_SYMBOL(g_ah));
    hipGetSymbolAddress((void**)&al,     HIP_SYMBOL(g_al));
    hipGetSymbolAddress((void**)&wh,     HIP_SYMBOL(g_wh));
    hipGetSymbolAddress((void**)&wl,     HIP_SYMBOL(g_wl));
    hipGetSymbolAddress((void**)&dinv,   HIP_SYMBOL(g_dinv));
    hipGetSymbolAddress((void**)&degi,   HIP_SYMBOL(g_degi));
    hipGetSymbolAddress((void**)&cursor, HIP_SYMBOL(g_cursor));
    hipGetSymbolAddress((void**)&rowptr, HIP_SYMBOL(g_rowptr));
    hipGetSymbolAddress((void**)&csrsrc, HIP_SYMBOL(g_csrsrc));
    hipGetSymbolAddress((void**)&aS,     HIP_SYMBOL(g_aS));
    hipGetSymbolAddress((void**)&aD,     HIP_SYMBOL(g_aD));
    hipGetSymbolAddress((void**)&pool,   HIP_SYMBOL(g_pool));
    hipGetSymbolAddress((void**)&zb,     HIP_SYMBOL(g_zb));

    auto cdiv = [](int a, int b) { return (a + b - 1) / b; };
    int ggrid = cdiv(N_NODES, 128) * (H / 128);   // 391 * 6, swizzled in-kernel

    // ---- CSR build (per call; inputs re-restored each launch) ----
    fill_i32<<<cdiv(N_NODES,256),256,0,stream>>>(degi, N_NODES, 0);
    count_deg<<<cdiv(N_EDGES,256),256,0,stream>>>(dstp, degi);
    dinv_k<<<cdiv(N_NODES,256),256,0,stream>>>(degi, dinv);
    scan_rowptr<<<1,1024,0,stream>>>(degi, rowptr, cursor);
    bin_edges<<<cdiv(N_EDGES,256),256,0,stream>>>(srcp, dstp, cursor, csrsrc);

    // ---- GCN1 (K=3 GEMM stays fp32 vector) ----
    gemm_k3<<<cdiv(N_NODES*H,256),256,0,stream>>>(x, w1, bufA);
    gcn_gather<<<N_NODES,192,0,stream>>>(rowptr, csrsrc, bufA, dinv, b1, ah, al);

    // ---- GCN2 ----
    split_wT<<<cdiv(H*H,256),256,0,stream>>>(w2, wh, wl);
    gemm_bf16x3<<<ggrid,256,0,stream>>>(ah, al, wh, wl, bufA, N_NODES);
    gcn_gather<<<N_NODES,192,0,stream>>>(rowptr, csrsrc, bufA, dinv, b2, ah, al);

    // ---- GCN3 ----
    split_wT<<<cdiv(H*H,256),256,0,stream>>>(w3, wh, wl);
    gemm_bf16x3<<<ggrid,256,0,stream>>>(ah, al, wh, wl, bufA, N_NODES);
    gcn_gather<<<N_NODES,192,0,stream>>>(rowptr, csrsrc, bufA, dinv, b3, ah, al);

    // ---- GAT1 ----
    split_wT<<<cdiv(H*H,256),256,0,stream>>>(wg1, wh, wl);
    gemm_bf16x3<<<ggrid,256,0,stream>>>(ah, al, wh, wl, bufA, N_NODES);
    gat_alpha<<<cdiv(N_NODES*NH,256),256,0,stream>>>(bufA, as1, ad1, aS, aD);
    gat_gather<<<N_NODES,192,0,stream>>>(rowptr, csrsrc, bufA, aS, aD, bg1,
                                         (float*)nullptr, ah, al, 1);

    // ---- GAT2 (no relu; fp32 out for pooling) ----
    split_wT<<<cdiv(H*H,256),256,0,stream>>>(wg2, wh, wl);
    gemm_bf16x3<<<ggrid,256,0,stream>>>(ah, al, wh, wl, bufA, N_NODES);
    gat_alpha<<<cdiv(N_NODES*NH,256),256,0,stream>>>(bufA, as2, ad2, aS, aD);
    gat_gather<<<N_NODES,192,0,stream>>>(rowptr, csrsrc, bufA, aS, aD, bg2,
                                         bufB, (unsigned short*)nullptr, (unsigned short*)nullptr, 0);

    // ---- pool + classifier ----
    pool_graph<<<NG,192,0,stream>>>(batch, bufB, pool);
    mlp1<<<cdiv(NG*H2,256),256,0,stream>>>(pool, wc1, bc1, zb);
    mlp2<<<cdiv(NG*NC,64),64,0,stream>>>(zb, wc2, bc2, (float*)d_out);
}

// Round 6
// 2168.336 us; speedup vs baseline: 6.4198x; 1.3123x over previous
//
#include <hip/hip_runtime.h>
#include <math.h>

#define N_NODES 50000
#define N_EDGES 100000
#define H 768
#define NH 12
#define HD 64
#define NG 64
#define NC 10
#define H2 384

typedef __attribute__((ext_vector_type(8))) short          bfrag;   // 8 bf16 (4 VGPR)
typedef __attribute__((ext_vector_type(4))) float          ffrag;   // MFMA acc

// ---------------- static device scratch ----------------
__device__ float          g_bufA[(size_t)N_NODES * H];
__device__ float          g_bufB[(size_t)N_NODES * H];
__device__ unsigned short g_ah[(size_t)N_NODES * H];   // activation hi bf16
__device__ unsigned short g_al[(size_t)N_NODES * H];   // activation lo bf16
__device__ unsigned short g_wh[H * H];                 // weight^T hi bf16 [N][K]
__device__ unsigned short g_wl[H * H];                 // weight^T lo bf16
__device__ float          g_dinv[N_NODES];
__device__ int            g_degi[N_NODES];
__device__ int            g_cursor[N_NODES];
__device__ int            g_rowptr[N_NODES + 1];
__device__ int            g_csrsrc[N_EDGES];
__device__ float          g_aS[(size_t)N_NODES * NH];
__device__ float          g_aD[(size_t)N_NODES * NH];
__device__ float          g_pool[NG * H];
__device__ float          g_zb[NG * H2];

__device__ inline int clampi(int v, int hi) { return (v < 0) ? 0 : (v >= hi ? hi - 1 : v); }

__device__ inline unsigned short bf16rn(float f) {
    unsigned u = __float_as_uint(f);
    unsigned r = u + 0x7fffu + ((u >> 16) & 1u);   // RNE; inputs finite
    return (unsigned short)(r >> 16);
}
__device__ inline float bf16f(unsigned short h) { return __uint_as_float((unsigned)h << 16); }

// async global->LDS, 16B per lane: lane i writes lds_base + i*16 (wave-uniform base)
__device__ inline void gload_lds16(const unsigned short* g, unsigned short* s) {
    __builtin_amdgcn_global_load_lds(
        (const __attribute__((address_space(1))) void*)g,
        (__attribute__((address_space(3))) void*)s, 16, 0, 0);
}

// ---------------- CSR build ----------------
__global__ void fill_i32(int* p, int n, int v) {
    int i = blockIdx.x * blockDim.x + threadIdx.x;
    if (i < n) p[i] = v;
}

__global__ void count_deg(const int* __restrict__ dst, int* __restrict__ degi) {
    int e = blockIdx.x * blockDim.x + threadIdx.x;
    if (e < N_EDGES) atomicAdd(&degi[clampi(dst[e], N_NODES)], 1);
}

__global__ void dinv_k(const int* __restrict__ degi, float* __restrict__ dinv) {
    int i = blockIdx.x * blockDim.x + threadIdx.x;
    if (i < N_NODES) dinv[i] = rsqrtf((float)degi[i] + 1.0f);   // +1 = self-loop
}

__global__ __launch_bounds__(1024) void scan_rowptr(const int* __restrict__ degi,
                                                    int* __restrict__ rowptr,
                                                    int* __restrict__ cursor) {
    __shared__ int buf[1024];
    __shared__ int carry;
    int tid = threadIdx.x;
    if (tid == 0) carry = 0;
    __syncthreads();
    for (int base = 0; base < N_NODES; base += 1024) {
        int idx = base + tid;
        int v = (idx < N_NODES) ? degi[idx] : 0;
        buf[tid] = v;
        __syncthreads();
        for (int off = 1; off < 1024; off <<= 1) {
            int t = (tid >= off) ? buf[tid - off] : 0;
            __syncthreads();
            buf[tid] += t;
            __syncthreads();
        }
        if (idx < N_NODES) {
            int excl = buf[tid] - v + carry;
            rowptr[idx] = excl;
            cursor[idx] = excl;
        }
        int total = buf[1023];
        __syncthreads();
        if (tid == 0) carry += total;
        __syncthreads();
    }
    if (tid == 0) rowptr[N_NODES] = carry;
}

__global__ void bin_edges(const int* __restrict__ src, const int* __restrict__ dst,
                          int* __restrict__ cursor, int* __restrict__ csrsrc) {
    int e = blockIdx.x * blockDim.x + threadIdx.x;
    if (e >= N_EDGES) return;
    int d = clampi(dst[e], N_NODES);
    int pos = atomicAdd(&cursor[d], 1);
    if (pos >= 0 && pos < N_EDGES) csrsrc[pos] = clampi(src[e], N_NODES);
}

// ---------------- GEMM: x@w1 (K=3) ----------------
__global__ void gemm_k3(const float* __restrict__ x, const float* __restrict__ w,
                        float* __restrict__ out) {
    int idx = blockIdx.x * blockDim.x + threadIdx.x;
    if (idx >= N_NODES * H) return;
    int n = idx / H, j = idx % H;
    float x0 = x[n*3], x1 = x[n*3+1], x2 = x[n*3+2];
    out[idx] = x0 * w[j] + x1 * w[H + j] + x2 * w[2*H + j];
}

// weights: w[K][N] fp32 -> transposed hi/lo bf16 [N][K]
__global__ void split_wT(const float* __restrict__ w, unsigned short* __restrict__ hi,
                         unsigned short* __restrict__ lo) {
    int idx = blockIdx.x * blockDim.x + threadIdx.x;   // over H*H
    if (idx >= H * H) return;
    int n = idx % H, k = idx / H;                      // read coalesced in n
    float v = w[(size_t)k * H + n];
    unsigned short h = bf16rn(v);
    hi[(size_t)n * H + k] = h;
    lo[(size_t)n * H + k] = bf16rn(v - bf16f(h));
}

// ---------------- bf16x3 MFMA GEMM ----------------
// C[M,768] = A[M,768] @ W; A,W pre-split bf16 hi/lo; W transposed [N][K].
// 128x128 tile, 256 threads (4 waves), wave = 64x64 via 4x4 of 16x16x32 MFMA.
// Staging via global_load_lds width=16, wave-specialized (wave w stages one of
// Ah/Al/Bh/Bl). LDS rows unpadded (LDA=32 ushorts = 64 B): with the quad*16B
// fragment offset this partitions all 32 banks into 8 groups x 8 lanes = the
// 8-cycle b128 floor, conflict-free — and matches global_load_lds's forced
// lane-contiguous layout.
// Swizzle: strip = (id&7) + 8*((id>>3)/6) so a strip's 6 col-tiles land on the
// SAME XCD (round-robin dispatch) back-to-back -> A strip L2-resident.
// (Round-4/5 evidence: consecutive-id grouping gave zero FETCH_SIZE change.)
__global__ __launch_bounds__(256) void gemm_bf16x3(const unsigned short* __restrict__ ah,
                                                   const unsigned short* __restrict__ al,
                                                   const unsigned short* __restrict__ bth,
                                                   const unsigned short* __restrict__ btl,
                                                   float* __restrict__ C, int M) {
    __shared__ unsigned short sAh[128 * 32], sAl[128 * 32];
    __shared__ unsigned short sBh[128 * 32], sBl[128 * 32];
    int tid = threadIdx.x;
    int wave = tid >> 6, lane = tid & 63;
    int quad = lane >> 4, l16 = lane & 15;

    int id = blockIdx.x;
    int x = id & 7;            // XCD slot (round-robin assumption; harmless if wrong)
    int s = id >> 3;
    int strip = x + 8 * (s / 6);
    int colt = s % 6;
    if (strip >= (N_NODES + 127) / 128) return;
    int row0 = strip * 128, col0 = colt * 128;
    int wr = (wave >> 1) * 64, wc = (wave & 1) * 64;

    // this wave's staging assignment
    const unsigned short* gsrc;
    unsigned short* sdst;
    int gbase;
    if (wave == 0)      { gsrc = ah;  sdst = sAh; gbase = row0; }
    else if (wave == 1) { gsrc = al;  sdst = sAl; gbase = row0; }
    else if (wave == 2) { gsrc = bth; sdst = sBh; gbase = col0; }
    else                { gsrc = btl; sdst = sBl; gbase = col0; }
    int isA = (wave < 2);
    int rr = lane >> 2, kc = (lane & 3) << 3;   // 4 lanes per row, 8-ushort chunks

    ffrag acc[4][4];
    #pragma unroll
    for (int i = 0; i < 4; i++)
        #pragma unroll
        for (int j = 0; j < 4; j++) { ffrag z = {0.f, 0.f, 0.f, 0.f}; acc[i][j] = z; }

    for (int k0 = 0; k0 < H; k0 += 32) {
        // async stage: 8 segs x (16 rows x 32 k) = 128x32 per array
        #pragma unroll
        for (int seg = 0; seg < 8; seg++) {
            int r = gbase + seg * 16 + rr;
            if (isA && r >= M) r = M - 1;   // clamped rows feed unstored C rows
            gload_lds16(gsrc + (size_t)r * H + k0 + kc, sdst + seg * 512);
        }
        __syncthreads();

        bfrag fah[4], fal[4], fbh[4], fbl[4];
        #pragma unroll
        for (int i = 0; i < 4; i++) {
            int r = wr + i * 16 + l16;
            fah[i] = *reinterpret_cast<const bfrag*>(&sAh[r * 32 + quad * 8]);
            fal[i] = *reinterpret_cast<const bfrag*>(&sAl[r * 32 + quad * 8]);
        }
        #pragma unroll
        for (int j = 0; j < 4; j++) {
            int c = wc + j * 16 + l16;
            fbh[j] = *reinterpret_cast<const bfrag*>(&sBh[c * 32 + quad * 8]);
            fbl[j] = *reinterpret_cast<const bfrag*>(&sBl[c * 32 + quad * 8]);
        }
        #pragma unroll
        for (int i = 0; i < 4; i++)
            #pragma unroll
            for (int j = 0; j < 4; j++) {
                acc[i][j] = __builtin_amdgcn_mfma_f32_16x16x32_bf16(fah[i], fbh[j], acc[i][j], 0, 0, 0);
                acc[i][j] = __builtin_amdgcn_mfma_f32_16x16x32_bf16(fah[i], fbl[j], acc[i][j], 0, 0, 0);
                acc[i][j] = __builtin_amdgcn_mfma_f32_16x16x32_bf16(fal[i], fbh[j], acc[i][j], 0, 0, 0);
            }
        __syncthreads();
    }

    // epilogue: C/D layout col=lane&15, row=quad*4+reg (m89-verified)
    #pragma unroll
    for (int i = 0; i < 4; i++)
        #pragma unroll
        for (int r = 0; r < 4; r++) {
            int row = row0 + wr + i * 16 + quad * 4 + r;
            if (row >= M) continue;
            #pragma unroll
            for (int j = 0; j < 4; j++)
                C[(size_t)row * H + col0 + wc + j * 16 + l16] = acc[i][j][r];
        }
}

// ---------------- fused GCN gather (self + edges + bias + relu + bf16 split) ----
__global__ void gcn_gather(const int* __restrict__ rowptr, const int* __restrict__ csrsrc,
                           const float* __restrict__ h, const float* __restrict__ dinv,
                           const float* __restrict__ bias,
                           unsigned short* __restrict__ hi, unsigned short* __restrict__ lo) {
    int d = blockIdx.x;
    int t = threadIdx.x;
    float dd = dinv[d];
    float4 v = ((const float4*)(h + (size_t)d * H))[t];
    float c = dd * dd;
    float4 acc; acc.x = v.x * c; acc.y = v.y * c; acc.z = v.z * c; acc.w = v.w * c;
    int beg = rowptr[d], end = rowptr[d + 1];
    for (int i = beg; i < end; i++) {
        int s = csrsrc[i];
        float cc = dinv[s] * dd;
        float4 u = ((const float4*)(h + (size_t)s * H))[t];
        acc.x += u.x * cc; acc.y += u.y * cc; acc.z += u.z * cc; acc.w += u.w * cc;
    }
    float4 b = ((const float4*)bias)[t];
    acc.x = fmaxf(acc.x + b.x, 0.f); acc.y = fmaxf(acc.y + b.y, 0.f);
    acc.z = fmaxf(acc.z + b.z, 0.f); acc.w = fmaxf(acc.w + b.w, 0.f);
    ushort4 h4, l4;
    h4.x = bf16rn(acc.x); l4.x = bf16rn(acc.x - bf16f(h4.x));
    h4.y = bf16rn(acc.y); l4.y = bf16rn(acc.y - bf16f(h4.y));
    h4.z = bf16rn(acc.z); l4.z = bf16rn(acc.z - bf16f(h4.z));
    h4.w = bf16rn(acc.w); l4.w = bf16rn(acc.w - bf16f(h4.w));
    ((ushort4*)(hi + (size_t)d * H))[t] = h4;
    ((ushort4*)(lo + (size_t)d * H))[t] = l4;
}

// ---------------- GAT ----------------
__global__ void gat_alpha(const float* __restrict__ h, const float* __restrict__ as,
                          const float* __restrict__ ad, float* __restrict__ alpha_s,
                          float* __restrict__ alpha_d) {
    int idx = blockIdx.x * blockDim.x + threadIdx.x;
    if (idx >= N_NODES * NH) return;
    int n = idx / NH, hh = idx % NH;
    const float* hp  = h  + (size_t)n * H + hh * HD;
    const float* asp = as + hh * HD;
    const float* adp = ad + hh * HD;
    float ss = 0.f, sd = 0.f;
    for (int k = 0; k < HD; k++) { float v = hp[k]; ss += v * asp[k]; sd += v * adp[k]; }
    alpha_s[idx] = ss; alpha_d[idx] = sd;
}

__device__ inline float lrelu(float v) { return (v > 0.f) ? v : 0.2f * v; }

// fused softmax + weighted aggregation + bias (+relu); one block per dst node.
__global__ void gat_gather(const int* __restrict__ rowptr, const int* __restrict__ csrsrc,
                           const float* __restrict__ h, const float* __restrict__ aS,
                           const float* __restrict__ aD, const float* __restrict__ bias,
                           float* __restrict__ out,
                           unsigned short* __restrict__ hi, unsigned short* __restrict__ lo,
                           int relu) {
    int d = blockIdx.x;
    int t = threadIdx.x;
    int hh = t >> 4;
    int beg = rowptr[d], end = rowptr[d + 1];
    float adv = aD[d * NH + hh];
    float eself = lrelu(aS[d * NH + hh] + adv);
    float m = eself;
    for (int i = beg; i < end; i++)
        m = fmaxf(m, lrelu(aS[csrsrc[i] * NH + hh] + adv));
    float ssum = __expf(eself - m);
    for (int i = beg; i < end; i++)
        ssum += __expf(lrelu(aS[csrsrc[i] * NH + hh] + adv) - m);
    float inv = 1.0f / ssum;
    float cself = __expf(eself - m) * inv;
    float4 v = ((const float4*)(h + (size_t)d * H))[t];
    float4 acc; acc.x = v.x * cself; acc.y = v.y * cself; acc.z = v.z * cself; acc.w = v.w * cself;
    for (int i = beg; i < end; i++) {
        int s = csrsrc[i];
        float c = __expf(lrelu(aS[s * NH + hh] + adv) - m) * inv;
        float4 u = ((const float4*)(h + (size_t)s * H))[t];
        acc.x += u.x * c; acc.y += u.y * c; acc.z += u.z * c; acc.w += u.w * c;
    }
    float4 b = ((const float4*)bias)[t];
    acc.x += b.x; acc.y += b.y; acc.z += b.z; acc.w += b.w;
    if (relu) {
        acc.x = fmaxf(acc.x, 0.f); acc.y = fmaxf(acc.y, 0.f);
        acc.z = fmaxf(acc.z, 0.f); acc.w = fmaxf(acc.w, 0.f);
    }
    if (hi) {
        ushort4 h4, l4;
        h4.x = bf16rn(acc.x); l4.x = bf16rn(acc.x - bf16f(h4.x));
        h4.y = bf16rn(acc.y); l4.y = bf16rn(acc.y - bf16f(h4.y));
        h4.z = bf16rn(acc.z); l4.z = bf16rn(acc.z - bf16f(h4.z));
        h4.w = bf16rn(acc.w); l4.w = bf16rn(acc.w - bf16f(h4.w));
        ((ushort4*)(hi + (size_t)d * H))[t] = h4;
        ((ushort4*)(lo + (size_t)d * H))[t] = l4;
    } else {
        ((float4*)(out + (size_t)d * H))[t] = acc;
    }
}

// ---------------- pooling (batch is sorted) + classifier ----------------
__device__ inline int lower_bound_i(const int* b, int n, int key) {
    int lo = 0, hi = n;
    while (lo < hi) { int mid = (lo + hi) >> 1; if (b[mid] < key) lo = mid + 1; else hi = mid; }
    return lo;
}

__global__ void pool_graph(const int* __restrict__ batch, const float* __restrict__ h,
                           float* __restrict__ pool) {
    int g = blockIdx.x;   // NG blocks, 192 threads
    int t = threadIdx.x;
    int lo = lower_bound_i(batch, N_NODES, g);
    int hi = lower_bound_i(batch, N_NODES, g + 1);
    float4 a0 = {0,0,0,0}, a1 = {0,0,0,0}, a2 = {0,0,0,0}, a3 = {0,0,0,0};
    int n = lo;
    for (; n + 3 < hi; n += 4) {
        float4 v0 = ((const float4*)(h + (size_t)(n+0) * H))[t];
        float4 v1 = ((const float4*)(h + (size_t)(n+1) * H))[t];
        float4 v2 = ((const float4*)(h + (size_t)(n+2) * H))[t];
        float4 v3 = ((const float4*)(h + (size_t)(n+3) * H))[t];
        a0.x += v0.x; a0.y += v0.y; a0.z += v0.z; a0.w += v0.w;
        a1.x += v1.x; a1.y += v1.y; a1.z += v1.z; a1.w += v1.w;
        a2.x += v2.x; a2.y += v2.y; a2.z += v2.z; a2.w += v2.w;
        a3.x += v3.x; a3.y += v3.y; a3.z += v3.z; a3.w += v3.w;
    }
    for (; n < hi; n++) {
        float4 v = ((const float4*)(h + (size_t)n * H))[t];
        a0.x += v.x; a0.y += v.y; a0.z += v.z; a0.w += v.w;
    }
    float inv = 1.0f / fmaxf((float)(hi - lo), 1.0f);
    float4 o;
    o.x = (a0.x + a1.x + a2.x + a3.x) * inv;
    o.y = (a0.y + a1.y + a2.y + a3.y) * inv;
    o.z = (a0.z + a1.z + a2.z + a3.z) * inv;
    o.w = (a0.w + a1.w + a2.w + a3.w) * inv;
    ((float4*)(pool + (size_t)g * H))[t] = o;
}

__global__ void mlp1(const float* __restrict__ g, const float* __restrict__ w,
                     const float* __restrict__ b, float* __restrict__ z) {
    int idx = blockIdx.x * blockDim.x + threadIdx.x;
    if (idx >= NG * H2) return;
    int gg = idx / H2, j = idx % H2;
    const float* gp = g + (size_t)gg * H;
    float acc = b[j];
    for (int k = 0; k < H; k++) acc += gp[k] * w[(size_t)k * H2 + j];
    z[idx] = fmaxf(acc, 0.f);
}

__global__ void mlp2(const float* __restrict__ z, const float* __restrict__ w,
                     const float* __restrict__ b, float* __restrict__ out) {
    int idx = blockIdx.x * blockDim.x + threadIdx.x;
    if (idx >= NG * NC) return;
    int gg = idx / NC, c = idx % NC;
    const float* zp = z + (size_t)gg * H2;
    float acc = b[c];
    for (int k = 0; k < H2; k++) acc += zp[k] * w[(size_t)k * NC + c];
    out[idx] = acc;
}

// ---------------- launch ----------------
extern "C" void kernel_launch(void* const* d_in, const int* in_sizes, int n_in,
                              void* d_out, int out_size, void* d_ws, size_t ws_size,
                              hipStream_t stream) {
    (void)d_ws; (void)ws_size;
    const float* x     = (const float*)d_in[0];
    const int*   ei    = (const int*)d_in[1];
    const int*   batch = (const int*)d_in[2];
    const float* w1  = (const float*)d_in[3];  const float* b1  = (const float*)d_in[4];
    const float* w2  = (const float*)d_in[5];  const float* b2  = (const float*)d_in[6];
    const float* w3  = (const float*)d_in[7];  const float* b3  = (const float*)d_in[8];
    const float* wg1 = (const float*)d_in[9];  const float* as1 = (const float*)d_in[10];
    const float* ad1 = (const float*)d_in[11]; const float* bg1 = (const float*)d_in[12];
    const float* wg2 = (const float*)d_in[13]; const float* as2 = (const float*)d_in[14];
    const float* ad2 = (const float*)d_in[15]; const float* bg2 = (const float*)d_in[16];
    const float* wc1 = (const float*)d_in[17]; const float* bc1 = (const float*)d_in[18];
    const float* wc2 = (const float*)d_in[19]; const float* bc2 = (const float*)d_in[20];

    const int* srcp = ei;            // edge_index[0]
    const int* dstp = ei + N_EDGES;  // edge_index[1]

    float *bufA, *bufB, *dinv, *aS, *aD, *pool, *zb;
    unsigned short *ah, *al, *wh, *wl;
    int *degi, *cursor, *rowptr, *csrsrc;
    hipGetSymbolAddress((void**)&bufA,   HIP_SYMBOL(g_bufA));
    hipGetSymbolAddress((void**)&bufB,   HIP_SYMBOL(g_bufB));
    hipGetSymbolAddress((void**)&ah,     HIP_SYMBOL(g_ah));
    hipGetSymbolAddress((void**)&al,     HIP_SYMBOL(g_al));
    hipGetSymbolAddress((void**)&wh,     HIP_SYMBOL(g_wh));
    hipGetSymbolAddress((void**)&wl,     HIP_SYMBOL(g_wl));
    hipGetSymbolAddress((void**)&dinv,   HIP_SYMBOL(g_dinv));
    hipGetSymbolAddress((void**)&degi,   HIP_SYMBOL(g_degi));
    hipGetSymbolAddress((void**)&cursor, HIP_SYMBOL(g_cursor));
    hipGetSymbolAddress((void**)&rowptr, HIP_SYMBOL(g_rowptr));
    hipGetSymbolAddress((void**)&csrsrc, HIP_SYMBOL(g_csrsrc));
    hipGetSymbolAddress((void**)&aS,     HIP_SYMBOL(g_aS));
    hipGetSymbolAddress((void**)&aD,     HIP_SYMBOL(g_aD));
    hipGetSymbolAddress((void**)&pool,   HIP_SYMBOL(g_pool));
    hipGetSymbolAddress((void**)&zb,     HIP_SYMBOL(g_zb));

    auto cdiv = [](int a, int b) { return (a + b - 1) / b; };
    // 391 strips -> round up to 392 (8-aligned) x 6 col tiles; kernel guards spill
    int ggrid = 8 * cdiv(cdiv(N_NODES, 128), 8) * (H / 128) / 1;   // 2352

    // ---- CSR build (per call; inputs re-restored each launch) ----
    fill_i32<<<cdiv(N_NODES,256),256,0,stream>>>(degi, N_NODES, 0);
    count_deg<<<cdiv(N_EDGES,256),256,0,stream>>>(dstp, degi);
    dinv_k<<<cdiv(N_NODES,256),256,0,stream>>>(degi, dinv);
    scan_rowptr<<<1,1024,0,stream>>>(degi, rowptr, cursor);
    bin_edges<<<cdiv(N_EDGES,256),256,0,stream>>>(srcp, dstp, cursor, csrsrc);

    // ---- GCN1 (K=3 GEMM stays fp32 vector) ----
    gemm_k3<<<cdiv(N_NODES*H,256),256,0,stream>>>(x, w1, bufA);
    gcn_gather<<<N_NODES,192,0,stream>>>(rowptr, csrsrc, bufA, dinv, b1, ah, al);

    // ---- GCN2 ----
    split_wT<<<cdiv(H*H,256),256,0,stream>>>(w2, wh, wl);
    gemm_bf16x3<<<ggrid,256,0,stream>>>(ah, al, wh, wl, bufA, N_NODES);
    gcn_gather<<<N_NODES,192,0,stream>>>(rowptr, csrsrc, bufA, dinv, b2, ah, al);

    // ---- GCN3 ----
    split_wT<<<cdiv(H*H,256),256,0,stream>>>(w3, wh, wl);
    gemm_bf16x3<<<ggrid,256,0,stream>>>(ah, al, wh, wl, bufA, N_NODES);
    gcn_gather<<<N_NODES,192,0,stream>>>(rowptr, csrsrc, bufA, dinv, b3, ah, al);

    // ---- GAT1 ----
    split_wT<<<cdiv(H*H,256),256,0,stream>>>(wg1, wh, wl);
    gemm_bf16x3<<<ggrid,256,0,stream>>>(ah, al, wh, wl, bufA, N_NODES);
    gat_alpha<<<cdiv(N_NODES*NH,256),256,0,stream>>>(bufA, as1, ad1, aS, aD);
    gat_gather<<<N_NODES,192,0,stream>>>(rowptr, csrsrc, bufA, aS, aD, bg1,
                                         (float*)nullptr, ah, al, 1);

    // ---- GAT2 (no relu; fp32 out for pooling) ----
    split_wT<<<cdiv(H*H,256),256,0,stream>>>(wg2, wh, wl);
    gemm_bf16x3<<<ggrid,256,0,stream>>>(ah, al, wh, wl, bufA, N_NODES);
    gat_alpha<<<cdiv(N_NODES*NH,256),256,0,stream>>>(bufA, as2, ad2, aS, aD);
    gat_gather<<<N_NODES,192,0,stream>>>(rowptr, csrsrc, bufA, aS, aD, bg2,
                                         bufB, (unsigned short*)nullptr, (unsigned short*)nullptr, 0);

    // ---- pool + classifier ----
    pool_graph<<<NG,192,0,stream>>>(batch, bufB, pool);
    mlp1<<<cdiv(NG*H2,256),256,0,stream>>>(pool, wc1, bc1, zb);
    mlp2<<<cdiv(NG*NC,64),64,0,stream>>>(zb, wc2, bc2, (float*)d_out);
}